// Round 16
// baseline (30.320 us; speedup 1.0000x reference)
//
#include <hip/hip_runtime.h>
#include <hip/hip_bf16.h>

// RisingTideAttentionV2: out[m,:] = norm( exp(-||x_m - p_n|| / efft_n) ) @ V
// M=16384, N=4096, D=128. d2 = x2[m] + p2[n] - 2*dot(x_m,p_n). NEURON_SCALE=0.05125
//
// r16 = r12 main (best known) with the X f32->fp8 conversion + x2 FUSED into
// each block's staging phase (prep no longer touches X; main doesn't wait on
// an X pass). X-validity (||x||^2<=400, NaN) is a block-local LDS flag.
// Prep shrinks to P/pcg/V-scan + zeroing (388 blocks).
//
// Screen (r12): w = expf(-dist/efft) is EXACTLY 0.0f when dist >= 104*efft;
// thr = 106.75*efft. fp8 e4m3 K=128 MFMA (scales=1.0): |delta(2s)| <= 27
// given ||x||^2<=400, ||p||^2<=100 (guards enforce, else cold path).
// pc[n] = p2 - thr^2 - 32. all e = x2+pc-2s >= 0 (wave vote at end) ==> every
// weight exactly 0 ==> tile contributes 0 to numerator AND denominator ==>
// skip. Cold path: layout-free scalar f32 from RAW inputs (exact; spurious
// triggers are slow-but-correct). TLP experiments (r14/r15) falsified; back
// to (256,4) with 64 cols/wave.

typedef __attribute__((ext_vector_type(4))) float f32x4;
typedef __attribute__((ext_vector_type(4))) int   i32x4;
typedef __attribute__((ext_vector_type(8))) int   i32x8;

#define MTOT 16384
#define NTOT 4096
#define DD   128

__device__ __forceinline__ i32x4 pack16_fp8(f32x4 a0, f32x4 a1, f32x4 a2, f32x4 a3) {
    int w0 = __builtin_amdgcn_cvt_pk_fp8_f32(a0[0], a0[1], 0, false);
    w0     = __builtin_amdgcn_cvt_pk_fp8_f32(a0[2], a0[3], w0, true);
    int w1 = __builtin_amdgcn_cvt_pk_fp8_f32(a1[0], a1[1], 0, false);
    w1     = __builtin_amdgcn_cvt_pk_fp8_f32(a1[2], a1[3], w1, true);
    int w2 = __builtin_amdgcn_cvt_pk_fp8_f32(a2[0], a2[1], 0, false);
    w2     = __builtin_amdgcn_cvt_pk_fp8_f32(a2[2], a2[3], w2, true);
    int w3 = __builtin_amdgcn_cvt_pk_fp8_f32(a3[0], a3[1], 0, false);
    w3     = __builtin_amdgcn_cvt_pk_fp8_f32(a3[2], a3[3], w3, true);
    return (i32x4){w0, w1, w2, w3};
}

// ---------------- prep (no X work) ----------------
// blocks 0..127:   pos/temp -> Pb8, pcg; val finite-scan (32 n each)
// blocks 128..383: zero d_out (32 KB each)
// blocks 384..387: zero rsum_g; block 384 zeroes aflag
__global__ __launch_bounds__(256) void tide_prep(
    const float* __restrict__ pos, const float* __restrict__ val,
    const float* __restrict__ temp,
    char* __restrict__ Pb8, float* __restrict__ pcg,
    float* __restrict__ outz, float* __restrict__ rsz, int* __restrict__ aflag)
{
    const int bid = blockIdx.x, tid = threadIdx.x;
    if (bid < 128) {
        const int n = bid * 32 + (tid >> 3), seg = tid & 7;
        const float* ps = pos + (size_t)n * DD + seg * 16;
        f32x4 a0 = ((const f32x4*)ps)[0];
        f32x4 a1 = ((const f32x4*)ps)[1];
        f32x4 a2 = ((const f32x4*)ps)[2];
        f32x4 a3 = ((const f32x4*)ps)[3];
        *(i32x4*)(Pb8 + (size_t)n * DD + seg * 16) = pack16_fp8(a0, a1, a2, a3);
        float s = a0[0]*a0[0]+a0[1]*a0[1]+a0[2]*a0[2]+a0[3]*a0[3]
                + a1[0]*a1[0]+a1[1]*a1[1]+a1[2]*a1[2]+a1[3]*a1[3]
                + a2[0]*a2[0]+a2[1]*a2[1]+a2[2]*a2[2]+a2[3]*a2[3]
                + a3[0]*a3[0]+a3[1]*a3[1]+a3[2]*a3[2]+a3[3]*a3[3];
        s += __shfl_xor(s, 1); s += __shfl_xor(s, 2); s += __shfl_xor(s, 4);
        if (seg == 0) {
            if (!(s <= 100.f)) atomicOr(aflag, 1);   // NaN/Inf/out-of-model
            float efft = (fabsf(temp[n]) + 0.1f) * 0.05125f;
            float thr = 106.7459f * efft;           // 154*ln2
            float pcv = s - thr * thr - 32.0f;      // margin 32 covers fp8 err
            pcg[n] = pcv;
            if (!isfinite(pcv)) atomicOr(aflag, 1);
        }
        // V finite-scan (reference: 0-weight x NaN-V still taints output)
        const float* vs = val + (size_t)n * DD + seg * 16;
        f32x4 b0 = ((const f32x4*)vs)[0];
        f32x4 b1 = ((const f32x4*)vs)[1];
        f32x4 b2 = ((const f32x4*)vs)[2];
        f32x4 b3 = ((const f32x4*)vs)[3];
        float vchk = fabsf(b0[0])+fabsf(b0[1])+fabsf(b0[2])+fabsf(b0[3])
                   + fabsf(b1[0])+fabsf(b1[1])+fabsf(b1[2])+fabsf(b1[3])
                   + fabsf(b2[0])+fabsf(b2[1])+fabsf(b2[2])+fabsf(b2[3])
                   + fabsf(b3[0])+fabsf(b3[1])+fabsf(b3[2])+fabsf(b3[3]);
        if (!isfinite(vchk)) atomicOr(aflag, 1);
    } else if (bid < 384) {
        f32x4 z = {0.f, 0.f, 0.f, 0.f};
        float* dst = outz + (size_t)(bid - 128) * 8192;
        #pragma unroll
        for (int j = 0; j < 8; ++j)
            *(f32x4*)(dst + (size_t)j * 1024 + tid * 4) = z;
    } else {
        f32x4 z = {0.f, 0.f, 0.f, 0.f};
        float* dst = rsz + (size_t)(bid - 384) * 4096;
        #pragma unroll
        for (int j = 0; j < 4; ++j)
            *(f32x4*)(dst + (size_t)j * 1024 + tid * 4) = z;
        if (bid == 384 && tid == 0) aflag[0] = 0;
    }
}

// ---------------- main: fp8 K=128 screen, in-block X conversion ----------
// grid = 2048: blockIdx = mc*16 + nb. Block: rows mc*128..+127, cols nb*256..+255.
// Wave w owns 64 cols; pf8 loop-invariant (32 VGPR). Block converts its own
// 128-row X panel f32->fp8 into LDS (swizzled chunk layout) + computes x2.
__global__ __launch_bounds__(256, 4) void tide_main(
    const float* __restrict__ x,
    const char* __restrict__ Pb8, const float* __restrict__ pcg,
    const float* __restrict__ pos, const float* __restrict__ val,
    const float* __restrict__ temp,
    float* __restrict__ rsum_g, float* __restrict__ oaccum,
    const int* __restrict__ aflagp)
{
    __shared__ __attribute__((aligned(16))) char xpanel[128 * DD];  // 16 KB fp8
    __shared__ __attribute__((aligned(16))) float x2t[128];
    __shared__ int lds_bad;

    const int tid = threadIdx.x;
    const int wid = tid >> 6, lane = tid & 63;
    const int lo = lane & 15, hi = lane >> 4;
    const int nb = blockIdx.x & 15, mc = blockIdx.x >> 4;
    const int mb = mc * 128;
    const int c0 = nb * 256 + wid * 64;
    const int sc = 0x7F7F7F7F;   // e8m0 127 in every byte = scale 1.0

    if (tid == 0) lds_bad = 0;

    // loop-invariant P fragments: lane holds P[n=c0+f*16+lo][k-bytes hi*32..+32]
    // (A and B use the same (hi,byte)->k placement, so any HW k-permutation
    //  cancels in the dot product; C layout is the m89-verified 16x16 map.)
    i32x8 pf8[4];
    float pc[4];
    #pragma unroll
    for (int f = 0; f < 4; ++f) {
        const char* pb = Pb8 + (size_t)(c0 + f * 16 + lo) * DD + hi * 32;
        i32x4 plo = *(const i32x4*)pb;
        i32x4 phi = *(const i32x4*)(pb + 16);
        pf8[f] = (i32x8){plo[0], plo[1], plo[2], plo[3],
                         phi[0], phi[1], phi[2], phi[3]};
        pc[f] = pcg[c0 + f * 16 + lo];
    }

    __syncthreads();   // barrier A: lds_bad init visible before staging writes

    // ---- stage + convert X panel: thread t covers rows (t>>3)+32i; it
    // produces LDS chunk (t&7) of each row from GLOBAL chunk (t&7)^(row&7)
    // (pre-swizzle on the source; linear LDS dest; read side un-swizzles).
    // Also per-row x2 (8-lane shuffle reduce) + validity flag.
    const int srow = tid >> 3, sch = tid & 7;
    const int csrc = sch ^ (srow & 7);
    char* ld = xpanel + tid * 16;
    #pragma unroll
    for (int i = 0; i < 4; ++i) {
        const int row = srow + 32 * i;
        const float* src = x + (size_t)(mb + row) * DD + csrc * 16;
        f32x4 a0 = ((const f32x4*)src)[0];
        f32x4 a1 = ((const f32x4*)src)[1];
        f32x4 a2 = ((const f32x4*)src)[2];
        f32x4 a3 = ((const f32x4*)src)[3];
        *(i32x4*)(ld + i * 4096) = pack16_fp8(a0, a1, a2, a3);
        float s = a0[0]*a0[0]+a0[1]*a0[1]+a0[2]*a0[2]+a0[3]*a0[3]
                + a1[0]*a1[0]+a1[1]*a1[1]+a1[2]*a1[2]+a1[3]*a1[3]
                + a2[0]*a2[0]+a2[1]*a2[1]+a2[2]*a2[2]+a2[3]*a2[3]
                + a3[0]*a3[0]+a3[1]*a3[1]+a3[2]*a3[2]+a3[3]*a3[3];
        s += __shfl_xor(s, 1); s += __shfl_xor(s, 2); s += __shfl_xor(s, 4);
        if (sch == 0) {
            x2t[row] = s;
            if (!(s <= 400.f)) lds_bad = 1;   // NaN/Inf/out-of-model row
        }
    }
    __syncthreads();   // barrier B: panel + x2 + bad ready
    const int af = aflagp[0] | lds_bad;

    float em[4] = {3.4e38f, 3.4e38f, 3.4e38f, 3.4e38f};

    #pragma unroll
    for (int t = 0; t < 8; ++t) {
        // A-frag: row lo of subtile, k-bytes hi*32..+32 (chunks hi*2, hi*2+1)
        const char* xb = xpanel + (t * 16 + lo) * DD;
        i32x4 xa = *(const i32x4*)(xb + (((hi * 2)     ^ (lo & 7)) * 16));
        i32x4 xc = *(const i32x4*)(xb + (((hi * 2 + 1) ^ (lo & 7)) * 16));
        i32x8 xf8 = (i32x8){xa[0], xa[1], xa[2], xa[3],
                            xc[0], xc[1], xc[2], xc[3]};
        f32x4 x2r = *(const f32x4*)(x2t + t * 16 + hi * 4);

        f32x4 s0 = __builtin_amdgcn_mfma_scale_f32_16x16x128_f8f6f4(
            xf8, pf8[0], (f32x4){0.f,0.f,0.f,0.f}, 0, 0, 0, sc, 0, sc);
        f32x4 s1 = __builtin_amdgcn_mfma_scale_f32_16x16x128_f8f6f4(
            xf8, pf8[1], (f32x4){0.f,0.f,0.f,0.f}, 0, 0, 0, sc, 0, sc);
        f32x4 s2 = __builtin_amdgcn_mfma_scale_f32_16x16x128_f8f6f4(
            xf8, pf8[2], (f32x4){0.f,0.f,0.f,0.f}, 0, 0, 0, sc, 0, sc);
        f32x4 s3 = __builtin_amdgcn_mfma_scale_f32_16x16x128_f8f6f4(
            xf8, pf8[3], (f32x4){0.f,0.f,0.f,0.f}, 0, 0, 0, sc, 0, sc);

        #pragma unroll
        for (int r = 0; r < 4; ++r) {
            float e0 = fmaf(s0[r], -2.f, x2r[r] + pc[0]);
            float e1 = fmaf(s1[r], -2.f, x2r[r] + pc[1]);
            float e2 = fmaf(s2[r], -2.f, x2r[r] + pc[2]);
            float e3 = fmaf(s3[r], -2.f, x2r[r] + pc[3]);
            em[0] = fminf(em[0], e0); em[1] = fminf(em[1], e1);
            em[2] = fminf(em[2], e2); em[3] = fminf(em[3], e3);
        }
    }

    const float emin = fminf(fminf(em[0], em[1]), fminf(em[2], em[3]));
    const int bad = (!(emin >= 0.f)) | af;
    if (__builtin_expect(__any(bad), 0)) {
        // ---- cold exact path: scalar f32 from RAW inputs (layout-free) ----
        #pragma unroll 1
        for (int t = 0; t < 8; ++t) {
            #pragma unroll 1
            for (int f = 0; f < 4; ++f) {
                const int n = c0 + f * 16 + lo;
                float efft = (fabsf(temp[n]) + 0.1f) * 0.05125f;
                #pragma unroll 1
                for (int r = 0; r < 4; ++r) {
                    const int m = mb + t * 16 + hi * 4 + r;
                    float dot = 0.f, p2 = 0.f;
                    const float* xr = x + (size_t)m * DD;
                    const float* pr = pos + (size_t)n * DD;
                    #pragma unroll 4
                    for (int k = 0; k < DD; k += 4) {
                        f32x4 xv = *(const f32x4*)(xr + k);
                        f32x4 pv = *(const f32x4*)(pr + k);
                        dot = fmaf(xv[0], pv[0], dot); dot = fmaf(xv[1], pv[1], dot);
                        dot = fmaf(xv[2], pv[2], dot); dot = fmaf(xv[3], pv[3], dot);
                        p2  = fmaf(pv[0], pv[0], p2);  p2  = fmaf(pv[1], pv[1], p2);
                        p2  = fmaf(pv[2], pv[2], p2);  p2  = fmaf(pv[3], pv[3], p2);
                    }
                    float d2 = fmaxf(x2t[m - mb] + p2 - 2.f * dot, 0.f);
                    float wv = expf(-__builtin_amdgcn_sqrtf(d2) / efft);
                    if (wv != 0.f || af) {   // af: propagate 0*NaN-V like ref
                        atomicAdd(&rsum_g[m], wv);
                        const float* vr = val + (size_t)n * DD;
                        #pragma unroll 1
                        for (int dcol = 0; dcol < DD; ++dcol)
                            atomicAdd(&oaccum[(size_t)m * DD + dcol], wv * vr[dcol]);
                    }
                }
            }
        }
    }
}

// ---------------- normalize: only rows with nonzero rsum need work ----------
__global__ __launch_bounds__(256) void tide_norm(
    const float* __restrict__ rsum_g, float* __restrict__ outp)
{
    const int row = blockIdx.x * 256 + threadIdx.x;
    float s = rsum_g[row];
    if (s != 0.f) {
        float inv = 1.f / (s + 1e-8f);
        float* p = outp + (size_t)row * DD;
        #pragma unroll 4
        for (int j = 0; j < DD / 4; ++j) {
            f32x4 v = *(f32x4*)(p + j * 4);
            v[0] *= inv; v[1] *= inv; v[2] *= inv; v[3] *= inv;
            *(f32x4*)(p + j * 4) = v;
        }
    }
    // s == 0: out row already exact (0 / (0 + 1e-8) = 0, pre-zeroed)
}

extern "C" void kernel_launch(void* const* d_in, const int* in_sizes, int n_in,
                              void* d_out, int out_size, void* d_ws, size_t ws_size,
                              hipStream_t stream) {
    const float* x    = (const float*)d_in[0];  // [8,2048,128]
    const float* pos  = (const float*)d_in[1];  // [4096,128]
    const float* val  = (const float*)d_in[2];  // [4096,128]
    const float* temp = (const float*)d_in[3];  // [4096]
    float* out = (float*)d_out;

    char* ws = (char*)d_ws;
    char*  Pb8    = ws;                              // 512 KB
    float* pcg    = (float*)(ws + 524288);           // 16 KB
    float* rsum_g = (float*)(ws + 540672);           // 64 KB
    int*   aflag  = (int*)  (ws + 606208);           // 4 B

    hipLaunchKernelGGL(tide_prep, dim3(388), dim3(256), 0, stream,
                       pos, val, temp, Pb8, pcg, out, rsum_g, aflag);
    hipLaunchKernelGGL(tide_main, dim3(2048), dim3(256), 0, stream,
                       x, Pb8, pcg, pos, val, temp, rsum_g, out, aflag);
    hipLaunchKernelGGL(tide_norm, dim3(64), dim3(256), 0, stream,
                       rsum_g, out);
}

// Round 17
// 23.503 us; speedup vs baseline: 1.2900x; 1.2900x over previous
//
#include <hip/hip_runtime.h>
#include <hip/hip_bf16.h>

// RisingTideAttentionV2: out[m,:] = norm( exp(-||x_m - p_n|| / efft_n) ) @ V
// M=16384, N=4096, D=128. d2 = x2[m] + p2[n] - 2*dot(x_m,p_n). NEURON_SCALE=0.05125
//
// r17 = r12 (best, 23.6us) + screen folded into the MFMA C-operand:
// Xb8 stores fp8(-2x) (exact x2 scaling in fp8, same relative error), and
// mfma(A=-2x, B=p, C=x2+pc) emits e = x2 + pc - 2s DIRECTLY -- the 16
// per-subtile screen fmas vanish; min-reduce via nested fminf (min3-fusible).
// Margin bumped 32->40: false-negative requires true d <= 104*efft <= 4.8,
// capping Sum|x.p| <= (||p||+d)*||p|| <= 147 -> fp8 error <= 0.26*147 = 38.4
// < 40 (r12's 32 had a theoretical adversarial corner; data-irrelevant).
//
// Screen: w = expf(-dist/efft) is EXACTLY 0.0f when dist >= 104*efft;
// thr = 106.7459*efft (154*ln2). pc[n] = p2 - thr^2 - 40. all e >= 0 (wave
// vote at end) ==> every weight exactly 0 ==> tile contributes 0 to both
// numerator AND denominator ==> skip. Guards ||x||^2<=400, ||p||^2<=100
// (NaN/Inf fail them) else aflag -> cold. Cold path: layout-free scalar f32
// from RAW inputs (exact; spurious triggers slow-but-correct).

typedef __attribute__((ext_vector_type(4))) float f32x4;
typedef __attribute__((ext_vector_type(4))) int   i32x4;
typedef __attribute__((ext_vector_type(8))) int   i32x8;

#define MTOT 16384
#define NTOT 4096
#define DD   128

__device__ __forceinline__ i32x4 pack16_fp8(f32x4 a0, f32x4 a1, f32x4 a2, f32x4 a3) {
    int w0 = __builtin_amdgcn_cvt_pk_fp8_f32(a0[0], a0[1], 0, false);
    w0     = __builtin_amdgcn_cvt_pk_fp8_f32(a0[2], a0[3], w0, true);
    int w1 = __builtin_amdgcn_cvt_pk_fp8_f32(a1[0], a1[1], 0, false);
    w1     = __builtin_amdgcn_cvt_pk_fp8_f32(a1[2], a1[3], w1, true);
    int w2 = __builtin_amdgcn_cvt_pk_fp8_f32(a2[0], a2[1], 0, false);
    w2     = __builtin_amdgcn_cvt_pk_fp8_f32(a2[2], a2[3], w2, true);
    int w3 = __builtin_amdgcn_cvt_pk_fp8_f32(a3[0], a3[1], 0, false);
    w3     = __builtin_amdgcn_cvt_pk_fp8_f32(a3[2], a3[3], w3, true);
    return (i32x4){w0, w1, w2, w3};
}

// ---------------- prep ----------------
// blocks 0..511:    X -> fp8(-2x) Xb8 + x2g (32 rows each; 8 thr/row)
// blocks 512..639:  pos/temp -> Pb8, pcg; val finite-scan (32 n each)
// blocks 640..1151: zero d_out (16 KB each)
// blocks 1152..1155: zero rsum_g; block 1152 zeroes aflag
__global__ __launch_bounds__(256) void tide_prep(
    const float* __restrict__ x, const float* __restrict__ pos,
    const float* __restrict__ val, const float* __restrict__ temp,
    char* __restrict__ Xb8, float* __restrict__ x2g,
    char* __restrict__ Pb8, float* __restrict__ pcg,
    float* __restrict__ outz, float* __restrict__ rsz, int* __restrict__ aflag)
{
    const int bid = blockIdx.x, tid = threadIdx.x;
    if (bid < 512) {
        const int row = bid * 32 + (tid >> 3), seg = tid & 7;
        const float* src = x + (size_t)row * DD + seg * 16;
        f32x4 a0 = ((const f32x4*)src)[0];
        f32x4 a1 = ((const f32x4*)src)[1];
        f32x4 a2 = ((const f32x4*)src)[2];
        f32x4 a3 = ((const f32x4*)src)[3];
        // store fp8(-2x): MFMA then computes -2*dot directly
        *(i32x4*)(Xb8 + (size_t)row * DD + seg * 16) =
            pack16_fp8(a0 * -2.f, a1 * -2.f, a2 * -2.f, a3 * -2.f);
        float s = a0[0]*a0[0]+a0[1]*a0[1]+a0[2]*a0[2]+a0[3]*a0[3]
                + a1[0]*a1[0]+a1[1]*a1[1]+a1[2]*a1[2]+a1[3]*a1[3]
                + a2[0]*a2[0]+a2[1]*a2[1]+a2[2]*a2[2]+a2[3]*a2[3]
                + a3[0]*a3[0]+a3[1]*a3[1]+a3[2]*a3[2]+a3[3]*a3[3];
        s += __shfl_xor(s, 1); s += __shfl_xor(s, 2); s += __shfl_xor(s, 4);
        if (seg == 0) {
            x2g[row] = s;
            if (!(s <= 400.f)) atomicOr(aflag, 1);   // NaN/Inf/out-of-model
        }
    } else if (bid < 640) {
        const int n = (bid - 512) * 32 + (tid >> 3), seg = tid & 7;
        const float* ps = pos + (size_t)n * DD + seg * 16;
        f32x4 a0 = ((const f32x4*)ps)[0];
        f32x4 a1 = ((const f32x4*)ps)[1];
        f32x4 a2 = ((const f32x4*)ps)[2];
        f32x4 a3 = ((const f32x4*)ps)[3];
        *(i32x4*)(Pb8 + (size_t)n * DD + seg * 16) = pack16_fp8(a0, a1, a2, a3);
        float s = a0[0]*a0[0]+a0[1]*a0[1]+a0[2]*a0[2]+a0[3]*a0[3]
                + a1[0]*a1[0]+a1[1]*a1[1]+a1[2]*a1[2]+a1[3]*a1[3]
                + a2[0]*a2[0]+a2[1]*a2[1]+a2[2]*a2[2]+a2[3]*a2[3]
                + a3[0]*a3[0]+a3[1]*a3[1]+a3[2]*a3[2]+a3[3]*a3[3];
        s += __shfl_xor(s, 1); s += __shfl_xor(s, 2); s += __shfl_xor(s, 4);
        if (seg == 0) {
            if (!(s <= 100.f)) atomicOr(aflag, 1);
            float efft = (fabsf(temp[n]) + 0.1f) * 0.05125f;
            float thr = 106.7459f * efft;           // 154*ln2
            float pcv = s - thr * thr - 40.0f;      // margin 40 covers fp8 err
            pcg[n] = pcv;
            if (!isfinite(pcv)) atomicOr(aflag, 1);
        }
        // V finite-scan (reference: 0-weight x NaN-V still taints output)
        const float* vs = val + (size_t)n * DD + seg * 16;
        f32x4 b0 = ((const f32x4*)vs)[0];
        f32x4 b1 = ((const f32x4*)vs)[1];
        f32x4 b2 = ((const f32x4*)vs)[2];
        f32x4 b3 = ((const f32x4*)vs)[3];
        float vchk = fabsf(b0[0])+fabsf(b0[1])+fabsf(b0[2])+fabsf(b0[3])
                   + fabsf(b1[0])+fabsf(b1[1])+fabsf(b1[2])+fabsf(b1[3])
                   + fabsf(b2[0])+fabsf(b2[1])+fabsf(b2[2])+fabsf(b2[3])
                   + fabsf(b3[0])+fabsf(b3[1])+fabsf(b3[2])+fabsf(b3[3]);
        if (!isfinite(vchk)) atomicOr(aflag, 1);
    } else if (bid < 1152) {
        f32x4 z = {0.f, 0.f, 0.f, 0.f};
        float* dst = outz + (size_t)(bid - 640) * 4096;
        #pragma unroll
        for (int j = 0; j < 4; ++j)
            *(f32x4*)(dst + (size_t)(tid + 256 * j) * 4) = z;
    } else {
        f32x4 z = {0.f, 0.f, 0.f, 0.f};
        float* dst = rsz + (size_t)(bid - 1152) * 4096;
        #pragma unroll
        for (int j = 0; j < 4; ++j)
            *(f32x4*)(dst + (size_t)(tid + 256 * j) * 4) = z;
        if (bid == 1152 && tid == 0) aflag[0] = 0;
    }
}

// ---------------- main: fp8 K=128 screen with C-folded e ----------------
// grid = 2048: blockIdx = mc*16 + nb. Block: rows mc*128..+127, cols nb*256..+255.
// Wave w owns 64 cols; pf8 loop-invariant (32 VGPR). 16 KB fp8 X panel staged
// once via global_load_lds; 8 zero-sync subtiles of 2 ds_read + 4 MFMA(C=x2+pc)
// + min-tree. MFMA output IS the screen value e.
__global__ __launch_bounds__(256, 4) void tide_main(
    const char* __restrict__ Xb8, const float* __restrict__ x2g,
    const char* __restrict__ Pb8, const float* __restrict__ pcg,
    const float* __restrict__ x, const float* __restrict__ pos,
    const float* __restrict__ val, const float* __restrict__ temp,
    float* __restrict__ rsum_g, float* __restrict__ oaccum,
    const int* __restrict__ aflagp)
{
    __shared__ __attribute__((aligned(16))) char xpanel[128 * DD];  // 16 KB fp8
    __shared__ __attribute__((aligned(16))) float x2t[128];

    const int tid = threadIdx.x;
    const int wid = tid >> 6, lane = tid & 63;
    const int lo = lane & 15, hi = lane >> 4;
    const int nb = blockIdx.x & 15, mc = blockIdx.x >> 4;
    const int mb = mc * 128;
    const int c0 = nb * 256 + wid * 64;
    const int sc = 0x7F7F7F7F;   // e8m0 127 in every byte = scale 1.0

    // loop-invariant P fragments: lane holds P[n=c0+f*16+lo][k-bytes hi*32..+32]
    // (A and B use the same (hi,byte)->k placement, so any HW k-permutation
    //  cancels in the dot product; C layout is the m89-verified 16x16 map:
    //  col=lane&15, row=(lane>>4)*4+reg -- matches x2[row]+pc[col] exactly.)
    i32x8 pf8[4];
    float pc[4];
    #pragma unroll
    for (int f = 0; f < 4; ++f) {
        const char* pb = Pb8 + (size_t)(c0 + f * 16 + lo) * DD + hi * 32;
        i32x4 plo = *(const i32x4*)pb;
        i32x4 phi = *(const i32x4*)(pb + 16);
        pf8[f] = (i32x8){plo[0], plo[1], plo[2], plo[3],
                         phi[0], phi[1], phi[2], phi[3]};
        pc[f] = pcg[c0 + f * 16 + lo];
    }
    const int af = aflagp[0];

    // stage 128x128 fp8 panel once: thread t covers rows (t>>3)+32i, 16B chunk
    // t&7; source chunk pre-swizzled by row&7 ((t>>3)&7, i-invariant), linear dest.
    const int srow = tid >> 3, sch = tid & 7;
    const char* xs = Xb8 + (size_t)(mb + srow) * DD + ((sch ^ (srow & 7)) * 16);
    char* ld = xpanel + tid * 16;
    #pragma unroll
    for (int i = 0; i < 4; ++i)
        __builtin_amdgcn_global_load_lds(
            (const __attribute__((address_space(1))) void*)(xs + (size_t)i * 32 * DD),
            (__attribute__((address_space(3))) void*)(ld + i * 4096), 16, 0, 0);
    if (tid < 128) x2t[tid] = x2g[mb + tid];
    __syncthreads();   // the ONLY sync: panel + x2 ready

    float em[4] = {3.4e38f, 3.4e38f, 3.4e38f, 3.4e38f};

    #pragma unroll
    for (int t = 0; t < 8; ++t) {
        // A-frag: row lo of subtile, k-bytes hi*32..+32 (chunks hi*2, hi*2+1)
        const char* xb = xpanel + (t * 16 + lo) * DD;
        i32x4 xa = *(const i32x4*)(xb + (((hi * 2)     ^ (lo & 7)) * 16));
        i32x4 xc = *(const i32x4*)(xb + (((hi * 2 + 1) ^ (lo & 7)) * 16));
        i32x8 xf8 = (i32x8){xa[0], xa[1], xa[2], xa[3],
                            xc[0], xc[1], xc[2], xc[3]};
        f32x4 x2r = *(const f32x4*)(x2t + t * 16 + hi * 4);

        // C-in = x2[row] + pc[col]; MFMA adds -2*dot -> output IS e
        f32x4 cc0, cc1, cc2, cc3;
        #pragma unroll
        for (int r = 0; r < 4; ++r) {
            cc0[r] = x2r[r] + pc[0];
            cc1[r] = x2r[r] + pc[1];
            cc2[r] = x2r[r] + pc[2];
            cc3[r] = x2r[r] + pc[3];
        }
        f32x4 e0 = __builtin_amdgcn_mfma_scale_f32_16x16x128_f8f6f4(
            xf8, pf8[0], cc0, 0, 0, 0, sc, 0, sc);
        f32x4 e1 = __builtin_amdgcn_mfma_scale_f32_16x16x128_f8f6f4(
            xf8, pf8[1], cc1, 0, 0, 0, sc, 0, sc);
        f32x4 e2 = __builtin_amdgcn_mfma_scale_f32_16x16x128_f8f6f4(
            xf8, pf8[2], cc2, 0, 0, 0, sc, 0, sc);
        f32x4 e3 = __builtin_amdgcn_mfma_scale_f32_16x16x128_f8f6f4(
            xf8, pf8[3], cc3, 0, 0, 0, sc, 0, sc);

        // min-tree (min3-fusible nests)
        em[0] = fminf(em[0], fminf(fminf(e0[0], e0[1]), fminf(e0[2], e0[3])));
        em[1] = fminf(em[1], fminf(fminf(e1[0], e1[1]), fminf(e1[2], e1[3])));
        em[2] = fminf(em[2], fminf(fminf(e2[0], e2[1]), fminf(e2[2], e2[3])));
        em[3] = fminf(em[3], fminf(fminf(e3[0], e3[1]), fminf(e3[2], e3[3])));
    }

    const float emin = fminf(fminf(em[0], em[1]), fminf(em[2], em[3]));
    const int bad = (!(emin >= 0.f)) | af;
    if (__builtin_expect(__any(bad), 0)) {
        // ---- cold exact path: scalar f32 from RAW inputs (layout-free) ----
        #pragma unroll 1
        for (int t = 0; t < 8; ++t) {
            #pragma unroll 1
            for (int f = 0; f < 4; ++f) {
                const int n = c0 + f * 16 + lo;
                float efft = (fabsf(temp[n]) + 0.1f) * 0.05125f;
                #pragma unroll 1
                for (int r = 0; r < 4; ++r) {
                    const int m = mb + t * 16 + hi * 4 + r;
                    float dot = 0.f, p2 = 0.f;
                    const float* xr = x + (size_t)m * DD;
                    const float* pr = pos + (size_t)n * DD;
                    #pragma unroll 4
                    for (int k = 0; k < DD; k += 4) {
                        f32x4 xv = *(const f32x4*)(xr + k);
                        f32x4 pv = *(const f32x4*)(pr + k);
                        dot = fmaf(xv[0], pv[0], dot); dot = fmaf(xv[1], pv[1], dot);
                        dot = fmaf(xv[2], pv[2], dot); dot = fmaf(xv[3], pv[3], dot);
                        p2  = fmaf(pv[0], pv[0], p2);  p2  = fmaf(pv[1], pv[1], p2);
                        p2  = fmaf(pv[2], pv[2], p2);  p2  = fmaf(pv[3], pv[3], p2);
                    }
                    float d2 = fmaxf(x2t[m - mb] + p2 - 2.f * dot, 0.f);
                    float wv = expf(-__builtin_amdgcn_sqrtf(d2) / efft);
                    if (wv != 0.f || af) {   // af: propagate 0*NaN-V like ref
                        atomicAdd(&rsum_g[m], wv);
                        const float* vr = val + (size_t)n * DD;
                        #pragma unroll 1
                        for (int dcol = 0; dcol < DD; ++dcol)
                            atomicAdd(&oaccum[(size_t)m * DD + dcol], wv * vr[dcol]);
                    }
                }
            }
        }
    }
}

// ---------------- normalize: only rows with nonzero rsum need work ----------
__global__ __launch_bounds__(256) void tide_norm(
    const float* __restrict__ rsum_g, float* __restrict__ outp)
{
    const int row = blockIdx.x * 256 + threadIdx.x;
    float s = rsum_g[row];
    if (s != 0.f) {
        float inv = 1.f / (s + 1e-8f);
        float* p = outp + (size_t)row * DD;
        #pragma unroll 4
        for (int j = 0; j < DD / 4; ++j) {
            f32x4 v = *(f32x4*)(p + j * 4);
            v[0] *= inv; v[1] *= inv; v[2] *= inv; v[3] *= inv;
            *(f32x4*)(p + j * 4) = v;
        }
    }
    // s == 0: out row already exact (0 / (0 + 1e-8) = 0, pre-zeroed)
}

extern "C" void kernel_launch(void* const* d_in, const int* in_sizes, int n_in,
                              void* d_out, int out_size, void* d_ws, size_t ws_size,
                              hipStream_t stream) {
    const float* x    = (const float*)d_in[0];  // [8,2048,128]
    const float* pos  = (const float*)d_in[1];  // [4096,128]
    const float* val  = (const float*)d_in[2];  // [4096,128]
    const float* temp = (const float*)d_in[3];  // [4096]
    float* out = (float*)d_out;

    char* ws = (char*)d_ws;
    char*  Xb8    = ws;                              // 2 MB
    char*  Pb8    = ws + 2097152;                    // 512 KB
    float* x2g    = (float*)(ws + 2621440);          // 64 KB
    float* pcg    = (float*)(ws + 2686976);          // 16 KB
    float* rsum_g = (float*)(ws + 2703360);          // 64 KB
    int*   aflag  = (int*)  (ws + 2768896);          // 4 B

    hipLaunchKernelGGL(tide_prep, dim3(1156), dim3(256), 0, stream,
                       x, pos, val, temp, Xb8, x2g, Pb8, pcg, out, rsum_g, aflag);
    hipLaunchKernelGGL(tide_main, dim3(2048), dim3(256), 0, stream,
                       Xb8, x2g, Pb8, pcg, x, pos, val, temp, rsum_g, out, aflag);
    hipLaunchKernelGGL(tide_norm, dim3(64), dim3(256), 0, stream,
                       rsum_g, out);
}